// Round 11
// baseline (242.950 us; speedup 1.0000x reference)
//
#include <hip/hip_runtime.h>

// Spiking basal ganglia: T=512 serial LIF steps, B=256 circuits.
// R16: fat-granule zero-sync. Evidence: four different schedules converge
// at 77-83us / ~1.7 TB/s effective; per-CU BW tracks bytes-in-flight
// (vmcnt<=63 instruction cap => scalar loads max 16KB/wave); R13 showed 2.2x
// per-CU ingest with fat islands. This kernel: 256 blocks x 1 wave; block =
// (circuit-pair, array); float4/lane = 1KB contiguous per t; 32 loads in
// flight (A/B ping-pong 16x float4, static-indexed); 4 verbatim membrane
// chains per lane; ballot lo/hi popcounts -> exact integer counts
// (partition-invariant => bit-exact). XCD swizzle: 16 adjacent pairs per
// XCD => contiguous 16KB window of each t-row per XCD (DRAM row reuse).
// Cross-block combine via OUT IN PLACE (no d_ws -- R14's suspected killer):
// block (p,a) writes u8 counts into byte 2a of out[t][2p..2p+1]; phase 2
// (256 threads) masks bytes, runs the verbatim stn/gpi tail, overwrites
// with gates. Disjoint bytes; same-stream kernel ordering.

__global__ __launch_bounds__(64, 1) void bg_phase1(
    const float* __restrict__ x,      // [T,B,2]
    const float* __restrict__ dopa,   // [T,B]
    const float* __restrict__ Wd1,    // [128,2]
    const float* __restrict__ Wd2,    // [128,2]
    const float* __restrict__ nd1,    // [T,B,128]
    const float* __restrict__ nd2,    // [T,B,128]
    float* __restrict__ out)          // [T,B] -- receives packed u8 counts
{
#pragma clang fp contract(off)
    constexpr int T = 512, B = 256;
    constexpr size_t TSTRIDE = (size_t)B * 128;   // noise t-stride (floats)

    __shared__ float lds_xm[T][2][4];  // [t][circuit][{xx,xy,m1,m2}]: 16 KB

    const int beta = blockIdx.x;
    const int lane = threadIdx.x;      // one wave per block
    // XCD swizzle: xcd = beta&7 (round-robin dispatch); 16 adjacent pairs
    // per XCD -> each XCD reads a contiguous 16KB window of every t-row.
    const int xcd  = beta & 7;
    const int slot = beta >> 3;        // 0..31
    const int a    = slot & 1;         // 0 -> nd1/Wd1, 1 -> nd2/Wd2
    const int p    = xcd * 16 + (slot >> 1);   // circuit pair 0..127
    const int b0   = 2 * p;

    // ---- prologue: stage {x, modulators} for both circuits ----
    for (int t = lane; t < T; t += 64) {
        const float4 xv = *(const float4*)(x + (size_t)t * (B * 2) + b0 * 2);
        const float2 dv = *(const float2*)(dopa + (size_t)t * B + b0);
        lds_xm[t][0][0] = xv.x;  lds_xm[t][0][1] = xv.y;
        lds_xm[t][0][2] = 1.0f + dv.x * 0.5f;   // m1 (verbatim op)
        lds_xm[t][0][3] = 1.0f - dv.x * 0.3f;   // m2 (verbatim op)
        lds_xm[t][1][0] = xv.z;  lds_xm[t][1][1] = xv.w;
        lds_xm[t][1][2] = 1.0f + dv.y * 0.5f;
        lds_xm[t][1][3] = 1.0f - dv.y * 0.3f;
    }
    __syncthreads();

    // lane l<32: circuit b0, neurons 4l..4l+3; l>=32: circuit b0+1, same.
    const float* na = (a ? nd2 : nd1) + (size_t)b0 * 128 + 4 * lane;
    const float* Wa = a ? Wd2 : Wd1;
    const int cL  = lane >> 5;
    const int nb4 = 4 * (lane & 31);
    const float4 W01 = *(const float4*)(Wa + 2 * nb4);      // rows nb4, nb4+1
    const float4 W23 = *(const float4*)(Wa + 2 * nb4 + 4);  // rows nb4+2, +3

    float v0 = 0.0f, v1 = 0.0f, v2 = 0.0f, v3 = 0.0f;
    unsigned int cnt_reg = 0u;

    float4 arrA[16], arrB[16];

#define LOADG(dst, t0)                                                       \
    { _Pragma("unroll")                                                      \
      for (int k = 0; k < 16; ++k)                                           \
          dst[k] = *(const float4*)(na + (size_t)((t0) + k) * TSTRIDE); }

    // 16 steps x 4 neurons: verbatim R2..R15 op sequence (contract off).
#define PROCG(src, t0, lbase)                                                \
    { _Pragma("unroll")                                                      \
      for (int k = 0; k < 16; ++k) {                                         \
          const float4 xm = *(const float4*)&lds_xm[(t0) + k][cL][0];        \
          const float m = a ? xm.w : xm.z;                                   \
          const float d0 = __builtin_fmaf(xm.y, W01.y, xm.x * W01.x);        \
          const float I0 = d0 * m + src[k].x * 0.1f;                         \
          v0 = 0.8f * v0 + 0.2f * I0;                                        \
          const bool s0 = v0 >= 0.5f; v0 = s0 ? 0.0f : v0;                   \
          const float d1 = __builtin_fmaf(xm.y, W01.w, xm.x * W01.z);        \
          const float I1 = d1 * m + src[k].y * 0.1f;                         \
          v1 = 0.8f * v1 + 0.2f * I1;                                        \
          const bool s1 = v1 >= 0.5f; v1 = s1 ? 0.0f : v1;                   \
          const float d2 = __builtin_fmaf(xm.y, W23.y, xm.x * W23.x);        \
          const float I2 = d2 * m + src[k].z * 0.1f;                         \
          v2 = 0.8f * v2 + 0.2f * I2;                                        \
          const bool s2 = v2 >= 0.5f; v2 = s2 ? 0.0f : v2;                   \
          const float d3 = __builtin_fmaf(xm.y, W23.w, xm.x * W23.z);        \
          const float I3 = d3 * m + src[k].w * 0.1f;                         \
          v3 = 0.8f * v3 + 0.2f * I3;                                        \
          const bool s3 = v3 >= 0.5f; v3 = s3 ? 0.0f : v3;                   \
          const unsigned long long m0 = __ballot(s0);                        \
          const unsigned long long m1b = __ballot(s1);                       \
          const unsigned long long m2b = __ballot(s2);                       \
          const unsigned long long m3b = __ballot(s3);                       \
          const unsigned int cA = (unsigned int)(                            \
              __popcll(m0 & 0xFFFFFFFFull) + __popcll(m1b & 0xFFFFFFFFull) + \
              __popcll(m2b & 0xFFFFFFFFull) + __popcll(m3b & 0xFFFFFFFFull));\
          const unsigned int cB = (unsigned int)(                            \
              __popcll(m0 >> 32) + __popcll(m1b >> 32) +                     \
              __popcll(m2b >> 32) + __popcll(m3b >> 32));                    \
          const unsigned int pk = cA | (cB << 8);                            \
          cnt_reg = (lane == (lbase) + k) ? pk : cnt_reg;                    \
      } }

    LOADG(arrA, 0)
    LOADG(arrB, 16)
    for (int gp = 0; gp < 16; ++gp) {
        const int t0 = gp * 32;
        const int lb = (gp & 1) * 32;      // == t0 & 63
        PROCG(arrA, t0, lb)
        if (gp < 15) LOADG(arrA, t0 + 32)
        PROCG(arrB, t0 + 16, lb + 16)
        if (gp < 15) LOADG(arrB, t0 + 48)
        if (gp & 1) {
            // lane j holds counts for step tw+j; write u8s into out bytes.
            // Block (p,a) owns byte 2a of circuits b0 and b0+1 -> disjoint.
            const int tw = (gp - 1) * 32;
            unsigned char* ob =
                (unsigned char*)(out + (size_t)(tw + lane) * B + b0) + 2 * a;
            ob[0] = (unsigned char)(cnt_reg & 0xFFu);        // circuit b0
            ob[4] = (unsigned char)((cnt_reg >> 8) & 0xFFu); // circuit b0+1
        }
    }
#undef LOADG
#undef PROCG
}

__global__ __launch_bounds__(64, 1) void bg_phase2(
    float* __restrict__ out)          // in: packed counts; out: gates
{
#pragma clang fp contract(off)
    constexpr int T = 512, B = 256;
    const int b = blockIdx.x * 64 + threadIdx.x;
    const unsigned int* ib = (const unsigned int*)out + b;

    float v_stn = 0.0f, v_gpi = 0.0f;
    unsigned int A2[8], B2[8];

#define LOADG2(dst, t0)                                                      \
    { _Pragma("unroll")                                                      \
      for (int k = 0; k < 8; ++k) dst[k] = ib[(size_t)((t0) + k) * B]; }

    // verbatim R2..R15 stn/gpi op sequence; c1/c2 exact integer sums.
    // bytes 1,3 of each u32 are stale garbage -> masked off.
#define PROCG2(src, t0)                                                      \
    { _Pragma("unroll")                                                      \
      for (int k = 0; k < 8; ++k) {                                          \
          const int c1 = (int)(src[k] & 0xFFu);                              \
          const int c2 = (int)((src[k] >> 16) & 0xFFu);                      \
          const float mean1 = (float)c1 * 0.0078125f;                        \
          const float mean2 = (float)c2 * 0.0078125f;                        \
          const float I_stn = mean2 * 0.5f;                                  \
          v_stn = 0.8f * v_stn + 0.2f * I_stn;                               \
          const float s_stn = (v_stn >= 0.5f) ? 1.0f : 0.0f;                 \
          v_stn = (v_stn >= 0.5f) ? 0.0f : v_stn;                            \
          const float I_gpi = (0.4f + mean1 * -0.8f) + s_stn * 0.6f;         \
          v_gpi = 0.8f * v_gpi + 0.2f * I_gpi;                               \
          const float s_gpi = (v_gpi >= 0.5f) ? 1.0f : 0.0f;                 \
          v_gpi = (v_gpi >= 0.5f) ? 0.0f : v_gpi;                            \
          out[(size_t)((t0) + k) * B + b] = mean1 - s_gpi;                   \
      } }

    LOADG2(A2, 0)
    LOADG2(B2, 8)
    for (int g = 0; g < 32; ++g) {
        const int t0 = g * 16;
        PROCG2(A2, t0)
        if (g < 31) LOADG2(A2, t0 + 16)
        PROCG2(B2, t0 + 8)
        if (g < 31) LOADG2(B2, t0 + 24)
    }
#undef LOADG2
#undef PROCG2
}

extern "C" void kernel_launch(void* const* d_in, const int* in_sizes, int n_in,
                              void* d_out, int out_size, void* d_ws, size_t ws_size,
                              hipStream_t stream) {
    const float* x    = (const float*)d_in[0];
    const float* dopa = (const float*)d_in[1];
    // d_in[2] = rpe — unused by the reference
    const float* Wd1  = (const float*)d_in[3];
    const float* Wd2  = (const float*)d_in[4];
    const float* nd1  = (const float*)d_in[5];
    const float* nd2  = (const float*)d_in[6];
    float* out = (float*)d_out;

    bg_phase1<<<dim3(256), dim3(64), 0, stream>>>(x, dopa, Wd1, Wd2, nd1, nd2, out);
    bg_phase2<<<dim3(4), dim3(64), 0, stream>>>(out);
}